// Round 2
// baseline (1118.130 us; speedup 1.0000x reference)
//
#include <hip/hip_runtime.h>

// Phi4 action: out[b] = x^T K x + lamb * sum_sites (sum_ch x^2)^2
// K = mu*I - kappa*(periodic 4-neighbor adjacency), block-diag over channels, so
//   x^T K x = sum_ch [ mu*sum x^2 - 2*kappa*sum_sites x*(x_right + x_down) ]
// mu, kappa read from K on device (K[0,0]=mu, K[0,1]=-kappa); lamb fixed (not in K).
//
// One 1024-thread block per batch element (16 waves/CU for latency hiding).
// Each thread owns 4 consecutive sites in one row: float4 loads for self and
// down-neighbor; right-neighbor vector = (v.y, v.z, v.w, shfl(next.v.x)) since
// the 16 threads of a row live in the same 64-lane wave.

#define LL 64
#define NCH 4
#define NSITES (LL * LL)           // 4096
#define PER_BATCH (NCH * NSITES)   // 16384

__global__ __launch_bounds__(1024) void phi4_action_kernel(
    const float* __restrict__ x,   // [B, NCH, L, L]
    const float* __restrict__ K,   // [16384, 16384] (only K[0], K[1] touched)
    float* __restrict__ out)       // [B]
{
    const int b    = blockIdx.x;
    const int tid  = threadIdx.x;          // 0..1023
    const int lane = tid & 63;

    const float mu    = K[0];
    const float kappa = -K[1];
    const float lamb  = 0.02f;

    const float* __restrict__ xb = x + (size_t)b * PER_BATCH;

    const int s4 = tid << 2;               // first of 4 consecutive sites (same row)
    const int i  = s4 >> 6;                // row
    const int j0 = s4 & 63;                // col, multiple of 4 (16B aligned)
    const int id = (i + 1) & 63;           // down row (periodic)

    // 16 consecutive lanes cover one row; next thread in row (with wrap) holds
    // the float4 starting at (j0+4)&63.
    const int src_lane = (lane & 48) | ((lane + 1) & 15);

    float  acc = 0.0f;
    float4 sq  = make_float4(0.f, 0.f, 0.f, 0.f);

    #pragma unroll
    for (int c = 0; c < NCH; ++c) {
        const float* __restrict__ xc = xb + c * NSITES;
        const float4 v  = *(const float4*)(xc + (i  << 6) + j0);
        const float4 vd = *(const float4*)(xc + (id << 6) + j0);
        const float xnext = __shfl(v.x, src_lane, 64);   // right neighbor of 4th site

        const float dot_vv = v.x*v.x + v.y*v.y + v.z*v.z + v.w*v.w;
        const float dot_vr = v.x*v.y + v.y*v.z + v.z*v.w + v.w*xnext;
        const float dot_vd = v.x*vd.x + v.y*vd.y + v.z*vd.z + v.w*vd.w;

        acc += mu * dot_vv - 2.0f * kappa * (dot_vr + dot_vd);
        sq.x += v.x*v.x; sq.y += v.y*v.y; sq.z += v.z*v.z; sq.w += v.w*v.w;
    }
    acc += lamb * (sq.x*sq.x + sq.y*sq.y + sq.z*sq.z + sq.w*sq.w);

    // 64-lane wave reduction.
    #pragma unroll
    for (int off = 32; off > 0; off >>= 1)
        acc += __shfl_down(acc, off, 64);

    __shared__ float wave_sums[16];
    const int wave = tid >> 6;
    if (lane == 0) wave_sums[wave] = acc;
    __syncthreads();

    if (wave == 0) {                        // all 64 lanes of wave 0 participate
        float v = (lane < 16) ? wave_sums[lane] : 0.0f;
        #pragma unroll
        for (int off = 8; off > 0; off >>= 1)
            v += __shfl_down(v, off, 64);
        if (lane == 0) out[b] = v;
    }
}

extern "C" void kernel_launch(void* const* d_in, const int* in_sizes, int n_in,
                              void* d_out, int out_size, void* d_ws, size_t ws_size,
                              hipStream_t stream) {
    const float* x = (const float*)d_in[0];   // [256, 4, 64, 64] fp32
    const float* K = (const float*)d_in[1];   // [16384, 16384] fp32
    float* out     = (float*)d_out;           // [256] fp32

    const int B = in_sizes[0] / PER_BATCH;    // 256
    phi4_action_kernel<<<B, 1024, 0, stream>>>(x, K, out);
}